// Round 7
// baseline (76.003 us; speedup 1.0000x reference)
//
#include <hip/hip_runtime.h>
#include <hip/hip_bf16.h>
#include <math.h>

typedef short bf16x8 __attribute__((ext_vector_type(8)));
typedef float f32x4 __attribute__((ext_vector_type(4)));

#define B_HALF 2048
#define N_TOT  4096
#define D_DIM  128
#define K_DIM  512
#define BK     64
#define NGRP   32
#define NBLK   528   // triangular 32x32 tile grid (528 % 8 == 0)

// ---------------------------------------------------------------------------
// Completion counters (module .bss -> zero at load). Increment-only, nobody
// spins; every counter is reset by the final winner before kernel end ->
// deterministic across graph replays (pattern validated R5/R6).
// ---------------------------------------------------------------------------
__device__ unsigned done_rg[32 * 32];     // per-row-group completion (padded)
__device__ unsigned final_done;
__device__ float    partial_rg[32 * 32];  // per-row-group partials (padded)

// ---------------------------------------------------------------------------
// P0: unified bf16 features G + a[].
// G_i = [inv, var+mu2, sqrt2*mu*inv, -sqrt2*mu]  (k-blocks of 128)
// Symmetric KL sum = sum_k G_i[k] * G_j[sigma(k)], sigma: blocks 0<->1, 2<->3
//   check: G[2]_i*G[3]_j = (sqrt2 mu_i inv_i)(-sqrt2 mu_j) = -2 mu_i inv_i mu_j
// a_i = sum_d mu^2 * inv
// ---------------------------------------------------------------------------
__global__ __launch_bounds__(256) void prep_feat(
    const float* __restrict__ mu_x, const float* __restrict__ sigma_x,
    const float* __restrict__ mu_p, const float* __restrict__ sigma_p,
    __hip_bfloat16* __restrict__ Gf, float* __restrict__ a) {
  const int tid = threadIdx.x;
  const int wv = tid >> 6;        // wave -> row within group of 4
  const int ln = tid & 63;
  const int d0 = ln * 2;          // two d's per lane
  const float SQ2 = 1.41421356237309515f;
#pragma unroll
  for (int rr = 0; rr < 16; rr += 4) {
    const int row = blockIdx.x * 16 + rr + wv;
    const float* mup = (row < B_HALF) ? mu_x : mu_p;
    const float* sgp = (row < B_HALF) ? sigma_x : sigma_p;
    const int gi = row & (B_HALF - 1);
    const float2 m2 = *(const float2*)(mup + gi * D_DIM + d0);
    const float2 s2 = *(const float2*)(sgp + gi * D_DIM + d0);
    float var0 = s2.x * s2.x, inv0 = 1.0f / var0, vm0 = var0 + m2.x * m2.x;
    float var1 = s2.y * s2.y, inv1 = 1.0f / var1, vm1 = var1 + m2.y * m2.y;
    size_t base = (size_t)row * K_DIM;
    __hip_bfloat162 h;
#define PK2(OFF, X, Y)                                                        \
    h.x = __float2bfloat16(X); h.y = __float2bfloat16(Y);                     \
    *(__hip_bfloat162*)(Gf + base + (OFF) + d0) = h;
    PK2(0,   inv0, inv1)
    PK2(128, vm0, vm1)
    PK2(256, SQ2 * m2.x * inv0, SQ2 * m2.y * inv1)
    PK2(384, -SQ2 * m2.x, -SQ2 * m2.y)
#undef PK2
    float av = m2.x * m2.x * inv0 + m2.y * m2.y * inv1;
#pragma unroll
    for (int x = 1; x < 64; x <<= 1) av += __shfl_xor(av, x);
    if (ln == 0) a[row] = av;
  }
}

#define GLOAD16(src, dst)                                                     \
  __builtin_amdgcn_global_load_lds(                                           \
      (const __attribute__((address_space(1))) void*)(src),                   \
      (__attribute__((address_space(3))) void*)(dst), 16, 0, 0)

// ---------------------------------------------------------------------------
// P1: triangular 128x128 MFMA tile + fused two-sided LSE partials + inline
// winner reduction. Double-buffered LDS; B staging reads G with k-chunk
// permutation kk^2 (the sigma block swap). LDS linear dest + pre-swizzled
// global source, read-side XOR (rule #21).
// ---------------------------------------------------------------------------
__global__ __launch_bounds__(256, 2) void gemm_lse(
    const __hip_bfloat16* __restrict__ Gf, const float* __restrict__ a,
    float* __restrict__ lsep, float* __restrict__ pos,
    float* __restrict__ out, float to_add) {
  __shared__ char lt[2][128 * BK * 2];   // 2 x 16 KB
  __shared__ char rt[2][128 * BK * 2];   // 2 x 16 KB
  __shared__ float2 red[128][2];         // 2 KB (reused as reduce scratch)
  __shared__ int p2g[2];

  // XCD-chunked bijective swizzle: hw XCD = bid%8 gets contiguous tile range
  const int sb = (blockIdx.x & 7) * (NBLK / 8) + (blockIdx.x >> 3);
  int t = sb, rb = 0;
  while (t >= 32 - rb) { t -= 32 - rb; ++rb; }
  const int cb = rb + t;

  const int tid  = threadIdx.x;
  const int lane = tid & 63;
  const int wave = tid >> 6;
  const int rowBase = rb * 128, colBase = cb * 128;
  const int wr = wave >> 1, wc = wave & 1;
  const int lx = lane & 15;
  const int rq = lane >> 4;

  f32x4 acc[4][4];
#pragma unroll
  for (int m = 0; m < 4; ++m)
#pragma unroll
    for (int n = 0; n < 4; ++n) acc[m][n] = (f32x4){0.f, 0.f, 0.f, 0.f};

  const int ric   = lane >> 3;
  const int cbyte = ((lane & 7) * 16) ^ (ric << 4);
  const int swzk  = (lane & 7) << 4;
  const char* lsrc0 = (const char*)Gf + (size_t)rowBase * (K_DIM * 2);
  const char* rsrc0 = (const char*)Gf + (size_t)colBase * (K_DIM * 2);

  // A reads chunk KK; B reads chunk KK^2 (feature-block swap sigma)
#define STAGE(KK, NB)                                                         \
  {                                                                           \
    const char* ls = lsrc0 + (KK) * (BK * 2);                                 \
    const char* rs = rsrc0 + ((KK) ^ 2) * (BK * 2);                           \
    _Pragma("unroll")                                                         \
    for (int t4 = 0; t4 < 4; ++t4) {                                          \
      int chunk = wave * 4 + t4;                                              \
      GLOAD16(ls + (size_t)(chunk * 8 + ric) * (K_DIM * 2) + cbyte,           \
              &lt[NB][chunk * 1024]);                                         \
      GLOAD16(rs + (size_t)(chunk * 8 + ric) * (K_DIM * 2) + cbyte,           \
              &rt[NB][chunk * 1024]);                                         \
    }                                                                         \
  }

  STAGE(0, 0)
  __syncthreads();

  for (int kk = 0; kk < K_DIM / BK; ++kk) {
    const int cur = kk & 1;
    if (kk < K_DIM / BK - 1) STAGE(kk + 1, cur ^ 1)   // prefetch next chunk
#pragma unroll
    for (int ks = 0; ks < 2; ++ks) {
      bf16x8 af[4], bg[4];
      const int kb = ks * 64 + rq * 16;
#pragma unroll
      for (int m = 0; m < 4; ++m) {
        int row = wr * 64 + m * 16 + lx;
        af[m] = *(const bf16x8*)(&lt[cur][row * 128 + (kb ^ swzk)]);
      }
#pragma unroll
      for (int n = 0; n < 4; ++n) {
        int row = wc * 64 + n * 16 + lx;
        bg[n] = *(const bf16x8*)(&rt[cur][row * 128 + (kb ^ swzk)]);
      }
#pragma unroll
      for (int m = 0; m < 4; ++m)
#pragma unroll
        for (int n = 0; n < 4; ++n)
          acc[m][n] = __builtin_amdgcn_mfma_f32_16x16x32_bf16(af[m], bg[n], acc[m][n], 0, 0, 0);
    }
    __syncthreads();   // drains vmcnt (prefetch landed during MFMA) + barrier
  }
#undef STAGE

  // ---- fused epilogue (proven R3/R6) ----
  const float c0 = 640.0f;   // (D/2)/T
  const float c1 = 2.5f;     // 0.25/T
  float aR[4][4];
#pragma unroll
  for (int m = 0; m < 4; ++m)
#pragma unroll
    for (int v = 0; v < 4; ++v)
      aR[m][v] = a[rowBase + wr * 64 + m * 16 + rq * 4 + v];
  float aC[4];
#pragma unroll
  for (int n = 0; n < 4; ++n) aC[n] = a[colBase + wc * 64 + n * 16 + lx];

  // pass 1: acc -> S (diag -> -inf; positive logit += to_add, pos[] writes)
#pragma unroll
  for (int m = 0; m < 4; ++m)
#pragma unroll
    for (int n = 0; n < 4; ++n)
#pragma unroll
      for (int v = 0; v < 4; ++v) {
        int grow = rowBase + wr * 64 + m * 16 + rq * 4 + v;
        int gcol = colBase + wc * 64 + n * 16 + lx;
        float S = c0 - c1 * (acc[m][n][v] + aR[m][v] + aC[n]);
        if (gcol == grow) {
          S = -INFINITY;
        } else if (gcol == (grow ^ B_HALF)) {
          S += to_add;
          pos[grow] = S;   // S symmetric: also row gcol's positive
          pos[gcol] = S;
        }
        acc[m][n][v] = S;
      }

  // pass 2: row partials -> lsep[row][cb]
#pragma unroll
  for (int m = 0; m < 4; ++m)
#pragma unroll
    for (int v = 0; v < 4; ++v) {
      float pm = -INFINITY;
#pragma unroll
      for (int n = 0; n < 4; ++n) pm = fmaxf(pm, acc[m][n][v]);
#pragma unroll
      for (int x = 1; x < 16; x <<= 1) pm = fmaxf(pm, __shfl_xor(pm, x));
      float ps = 0.f;
#pragma unroll
      for (int n = 0; n < 4; ++n) ps += __expf(acc[m][n][v] - pm);
#pragma unroll
      for (int x = 1; x < 16; x <<= 1) ps += __shfl_xor(ps, x);
      if (lx == 0) red[wr * 64 + m * 16 + rq * 4 + v][wc] = make_float2(pm, ps);
    }
  __syncthreads();
  if (tid < 128) {
    float2 p0 = red[tid][0], p1 = red[tid][1];
    float M = fmaxf(p0.x, p1.x);
    float S = p0.y * __expf(p0.x - M) + p1.y * __expf(p1.x - M);
    lsep[(size_t)(rowBase + tid) * NGRP + cb] = M + logf(S);
  }

  // pass 3: column partials -> lsep[col][rb]  (off-diagonal tiles only)
  if (rb != cb) {
    __syncthreads();
#pragma unroll
    for (int n = 0; n < 4; ++n) {
      float cm = -INFINITY;
#pragma unroll
      for (int m = 0; m < 4; ++m)
#pragma unroll
        for (int v = 0; v < 4; ++v) cm = fmaxf(cm, acc[m][n][v]);
      cm = fmaxf(cm, __shfl_xor(cm, 16));
      cm = fmaxf(cm, __shfl_xor(cm, 32));
      float cs = 0.f;
#pragma unroll
      for (int m = 0; m < 4; ++m)
#pragma unroll
        for (int v = 0; v < 4; ++v) cs += __expf(acc[m][n][v] - cm);
      cs += __shfl_xor(cs, 16);
      cs += __shfl_xor(cs, 32);
      if (lane < 16) red[wc * 64 + n * 16 + lane][wr] = make_float2(cm, cs);
    }
    __syncthreads();
    if (tid < 128) {
      float2 p0 = red[tid][0], p1 = red[tid][1];
      float M = fmaxf(p0.x, p1.x);
      float S = p0.y * __expf(p0.x - M) + p1.y * __expf(p1.x - M);
      lsep[(size_t)(colBase + tid) * NGRP + rb] = M + logf(S);
    }
  }

  __syncthreads();   // all lsep/pos stores of this block issued

  // ---- winner counters; winners run the final reduction inline ----
  // row-group g receives exactly 32 increments: (32-g) tiles with rb==g
  // plus g off-diagonal tiles with cb==g.
  if (tid == 0) {
    p2g[0] = -1; p2g[1] = -1;
    unsigned v = __hip_atomic_fetch_add(&done_rg[rb * 32], 1u, __ATOMIC_ACQ_REL,
                                        __HIP_MEMORY_SCOPE_AGENT);
    if (v == 31u) p2g[0] = rb;
    if (rb != cb) {
      v = __hip_atomic_fetch_add(&done_rg[cb * 32], 1u, __ATOMIC_ACQ_REL,
                                 __HIP_MEMORY_SCOPE_AGENT);
      if (v == 31u) p2g[1] = cb;
    }
  }
  __syncthreads();

  float* fr = (float*)red;   // 256-float reduce scratch
#pragma unroll
  for (int s = 0; s < 2; ++s) {
    const int g = p2g[s];
    if (g < 0) continue;

    // P2: LSE-combine the 128 rows of group g (fixed per-row order)
    float contrib = 0.f;
    if (tid < 128) {
      const int row = g * 128 + tid;
      const float* lp = lsep + (size_t)row * NGRP;
      float M = lp[0];
#pragma unroll
      for (int k = 1; k < NGRP; ++k) M = fmaxf(M, lp[k]);
      float ssum = 0.f;
#pragma unroll
      for (int k = 0; k < NGRP; ++k) ssum += __expf(lp[k] - M);
      contrib = (M + logf(ssum)) - pos[row];
    }
    fr[tid] = contrib;
    __syncthreads();
#pragma unroll
    for (int off = 128; off > 0; off >>= 1) {
      if (tid < off) fr[tid] += fr[tid + off];
      __syncthreads();
    }
    if (tid == 0) {
      partial_rg[g * 32] = fr[0];
      unsigned v = __hip_atomic_fetch_add(&final_done, 1u, __ATOMIC_ACQ_REL,
                                          __HIP_MEMORY_SCOPE_AGENT);
      if (v == 31u) {
        // P3: fixed-order final sum -> deterministic
        float tot = 0.f;
        for (int k = 0; k < 32; ++k) tot += partial_rg[k * 32];
        out[0] = tot * (1.0f / 4096.0f);
        // reset counters for the next graph replay (all increments
        // happen-before here via the per-location RMW acquire chains)
        for (int k = 0; k < 32; ++k)
          __hip_atomic_store(&done_rg[k * 32], 0u, __ATOMIC_RELAXED,
                             __HIP_MEMORY_SCOPE_AGENT);
        __hip_atomic_store(&final_done, 0u, __ATOMIC_RELAXED,
                           __HIP_MEMORY_SCOPE_AGENT);
      }
    }
    __syncthreads();
  }
}

// ===========================================================================
extern "C" void kernel_launch(void* const* d_in, const int* in_sizes, int n_in,
                              void* d_out, int out_size, void* d_ws, size_t ws_size,
                              hipStream_t stream) {
  const float* mu_x    = (const float*)d_in[1];
  const float* sigma_x = (const float*)d_in[2];
  const float* mu_p    = (const float*)d_in[3];
  const float* sigma_p = (const float*)d_in[4];
  float* out = (float*)d_out;

  float to_add = (float)(-log((4095.0 - 1.0 / 5.0) / 4094.0));

  const size_t featB = (size_t)N_TOT * K_DIM * 2;   // 4 MB
  char* ws = (char*)d_ws;
  __hip_bfloat16* Gf = (__hip_bfloat16*)(ws);
  float* a    = (float*)(ws + featB);                    // 16 KB
  float* lsep = (float*)(ws + featB + 16384);            // 512 KB
  float* pos  = (float*)(ws + featB + 16384 + 524288);   // 16 KB

  prep_feat<<<dim3(256), dim3(256), 0, stream>>>(mu_x, sigma_x, mu_p, sigma_p,
                                                 Gf, a);
  gemm_lse<<<dim3(NBLK), dim3(256), 0, stream>>>(Gf, a, lsep, pos, out, to_add);
}

// Round 8
// 40.740 us; speedup vs baseline: 1.8656x; 1.8656x over previous
//
#include <hip/hip_runtime.h>
#include <hip/hip_bf16.h>
#include <math.h>

typedef short bf16x8 __attribute__((ext_vector_type(8)));
typedef float f32x4 __attribute__((ext_vector_type(4)));

#define B_HALF 2048
#define N_TOT  4096
#define D_DIM  128
#define K_DIM  512
#define NGRP   32
#define NBLK   528   // triangular 32x32 tile grid (528 % 8 == 0)
#define KSTEPS 16    // K chunks of 32

// winner counter for the final reduction (zero at load; winner resets ->
// deterministic across graph replays; increment-only, nobody spins). Only
// 16 RMWs total, in a tiny kernel AFTER the GEMM (R6-proven; R7 showed
// per-GEMM-block agent RMWs cost ~25 us in L2 writebacks).
__device__ unsigned red_done;

// ---------------------------------------------------------------------------
// P0: unified bf16 features G + a[].
// G_i = [inv, var+mu2, sqrt2*mu*inv, -sqrt2*mu]  (k-blocks of 128)
// Symmetric KL sum = sum_k G_i[k]*G_j[sigma(k)], sigma swaps blocks 0<->1,
// 2<->3 -> with BK=32 chunks that is chunk index kk ^ 4.
// a_i = sum_d mu^2 * inv
// ---------------------------------------------------------------------------
__global__ __launch_bounds__(256) void prep_feat(
    const float* __restrict__ mu_x, const float* __restrict__ sigma_x,
    const float* __restrict__ mu_p, const float* __restrict__ sigma_p,
    __hip_bfloat16* __restrict__ Gf, float* __restrict__ a) {
  const int tid = threadIdx.x;
  const int wv = tid >> 6;
  const int ln = tid & 63;
  const int d0 = ln * 2;
  const float SQ2 = 1.41421356237309515f;
#pragma unroll
  for (int rr = 0; rr < 16; rr += 4) {
    const int row = blockIdx.x * 16 + rr + wv;
    const float* mup = (row < B_HALF) ? mu_x : mu_p;
    const float* sgp = (row < B_HALF) ? sigma_x : sigma_p;
    const int gi = row & (B_HALF - 1);
    const float2 m2 = *(const float2*)(mup + gi * D_DIM + d0);
    const float2 s2 = *(const float2*)(sgp + gi * D_DIM + d0);
    float var0 = s2.x * s2.x, inv0 = 1.0f / var0, vm0 = var0 + m2.x * m2.x;
    float var1 = s2.y * s2.y, inv1 = 1.0f / var1, vm1 = var1 + m2.y * m2.y;
    size_t base = (size_t)row * K_DIM;
    __hip_bfloat162 h;
#define PK2(OFF, X, Y)                                                        \
    h.x = __float2bfloat16(X); h.y = __float2bfloat16(Y);                     \
    *(__hip_bfloat162*)(Gf + base + (OFF) + d0) = h;
    PK2(0,   inv0, inv1)
    PK2(128, vm0, vm1)
    PK2(256, SQ2 * m2.x * inv0, SQ2 * m2.y * inv1)
    PK2(384, -SQ2 * m2.x, -SQ2 * m2.y)
#undef PK2
    float av = m2.x * m2.x * inv0 + m2.y * m2.y * inv1;
#pragma unroll
    for (int x = 1; x < 64; x <<= 1) av += __shfl_xor(av, x);
    if (ln == 0) a[row] = av;
  }
}

#define GLOAD16(src, dst)                                                     \
  __builtin_amdgcn_global_load_lds(                                           \
      (const __attribute__((address_space(1))) void*)(src),                   \
      (__attribute__((address_space(3))) void*)(dst), 16, 0, 0)

// ---------------------------------------------------------------------------
// P1: triangular 128x128 MFMA tile, BK=32, ring-of-3 LDS, counted vmcnt
// (T3+T4): loads stay in flight across barriers; vmcnt(4) mid-loop, 0 only
// at the tail. 3 blocks/CU (LDS 50 KB). LDS linear dest + pre-swizzled
// global source; read-side XOR (rule #21).
//   LDS[r][q*16] = G[r][(q ^ (r&3))*16]  (q = 0..3, row pitch 64B)
// ---------------------------------------------------------------------------
__global__ __launch_bounds__(256, 3) void gemm_lse(
    const __hip_bfloat16* __restrict__ Gf, const float* __restrict__ a,
    float* __restrict__ lsep, float* __restrict__ pos, float to_add) {
  __shared__ char lt[3][128 * 64];   // 3 x 8 KB
  __shared__ char rt[3][128 * 64];   // 3 x 8 KB
  __shared__ float2 red[128][2];     // 2 KB

  // XCD-chunked bijective swizzle
  const int sb = (blockIdx.x & 7) * (NBLK / 8) + (blockIdx.x >> 3);
  int t = sb, rb = 0;
  while (t >= 32 - rb) { t -= 32 - rb; ++rb; }
  const int cb = rb + t;

  const int tid  = threadIdx.x;
  const int lane = tid & 63;
  const int wave = tid >> 6;
  const int rowBase = rb * 128, colBase = cb * 128;
  const int wr = wave >> 1, wc = wave & 1;
  const int lx = lane & 15;
  const int rq = lane >> 4;

  f32x4 acc[4][4];
#pragma unroll
  for (int m = 0; m < 4; ++m)
#pragma unroll
    for (int n = 0; n < 4; ++n) acc[m][n] = (f32x4){0.f, 0.f, 0.f, 0.f};

  // staging geometry (per GLOAD16: 16 rows x 64B = 1 KB)
  const int sr  = lane >> 2;                       // sub-row 0..15
  const int scb = (((lane & 3) ^ (sr & 3)) << 4);  // pre-swizzled src colbyte
  const char* lsrc0 = (const char*)Gf + (size_t)rowBase * (K_DIM * 2);
  const char* rsrc0 = (const char*)Gf + (size_t)colBase * (K_DIM * 2);

  // A reads chunk KK; B reads chunk KK^4 (feature-block swap sigma)
#define STAGE(KK)                                                             \
  {                                                                           \
    const int b_ = (KK) % 3;                                                  \
    const char* ls_ = lsrc0 + (KK) * 64;                                      \
    const char* rs_ = rsrc0 + ((KK) ^ 4) * 64;                                \
    _Pragma("unroll")                                                         \
    for (int g = 0; g < 2; ++g) {                                             \
      const int row_ = wave * 32 + g * 16;                                    \
      GLOAD16(ls_ + (size_t)(row_ + sr) * 1024 + scb, &lt[b_][row_ * 64]);    \
      GLOAD16(rs_ + (size_t)(row_ + sr) * 1024 + scb, &rt[b_][row_ * 64]);    \
    }                                                                         \
  }

  STAGE(0)
  STAGE(1)

#pragma unroll
  for (int kk = 0; kk < KSTEPS; ++kk) {
    // counted drain: stage(kk) must be landed; stage(kk+1) stays in flight
    if (kk < KSTEPS - 1) asm volatile("s_waitcnt vmcnt(4)" ::: "memory");
    else                 asm volatile("s_waitcnt vmcnt(0)" ::: "memory");
    __builtin_amdgcn_s_barrier();
    __builtin_amdgcn_sched_barrier(0);   // no reads hoisted above the barrier
    if (kk + 2 < KSTEPS) STAGE(kk + 2)   // into buf (kk+2)%3 == (kk-1)%3: free
    const int b = kk % 3;
    bf16x8 af[4], bg[4];
    const int kbp = ((rq ^ (lx & 3)) << 4);   // read-side swizzled colbyte
#pragma unroll
    for (int m = 0; m < 4; ++m) {
      const int row = wr * 64 + m * 16 + lx;
      af[m] = *(const bf16x8*)(&lt[b][row * 64 + kbp]);
    }
#pragma unroll
    for (int n = 0; n < 4; ++n) {
      const int row = wc * 64 + n * 16 + lx;
      bg[n] = *(const bf16x8*)(&rt[b][row * 64 + kbp]);
    }
#pragma unroll
    for (int m = 0; m < 4; ++m)
#pragma unroll
      for (int n = 0; n < 4; ++n)
        acc[m][n] = __builtin_amdgcn_mfma_f32_16x16x32_bf16(af[m], bg[n], acc[m][n], 0, 0, 0);
  }
#undef STAGE

  // ---- fused epilogue (R3/R6-proven) ----
  const float c0 = 640.0f;   // (D/2)/T
  const float c1 = 2.5f;     // 0.25/T
  float aR[4][4];
#pragma unroll
  for (int m = 0; m < 4; ++m)
#pragma unroll
    for (int v = 0; v < 4; ++v)
      aR[m][v] = a[rowBase + wr * 64 + m * 16 + rq * 4 + v];
  float aC[4];
#pragma unroll
  for (int n = 0; n < 4; ++n) aC[n] = a[colBase + wc * 64 + n * 16 + lx];

  // pass 1: acc -> S (diag -> -inf; positive logit += to_add, pos[] writes)
#pragma unroll
  for (int m = 0; m < 4; ++m)
#pragma unroll
    for (int n = 0; n < 4; ++n)
#pragma unroll
      for (int v = 0; v < 4; ++v) {
        int grow = rowBase + wr * 64 + m * 16 + rq * 4 + v;
        int gcol = colBase + wc * 64 + n * 16 + lx;
        float S = c0 - c1 * (acc[m][n][v] + aR[m][v] + aC[n]);
        if (gcol == grow) {
          S = -INFINITY;
        } else if (gcol == (grow ^ B_HALF)) {
          S += to_add;
          pos[grow] = S;   // S symmetric: also row gcol's positive
          pos[gcol] = S;
        }
        acc[m][n][v] = S;
      }

  // pass 2: row partials -> lsep[row][cb]
#pragma unroll
  for (int m = 0; m < 4; ++m)
#pragma unroll
    for (int v = 0; v < 4; ++v) {
      float pm = -INFINITY;
#pragma unroll
      for (int n = 0; n < 4; ++n) pm = fmaxf(pm, acc[m][n][v]);
#pragma unroll
      for (int x = 1; x < 16; x <<= 1) pm = fmaxf(pm, __shfl_xor(pm, x));
      float ps = 0.f;
#pragma unroll
      for (int n = 0; n < 4; ++n) ps += __expf(acc[m][n][v] - pm);
#pragma unroll
      for (int x = 1; x < 16; x <<= 1) ps += __shfl_xor(ps, x);
      if (lx == 0) red[wr * 64 + m * 16 + rq * 4 + v][wc] = make_float2(pm, ps);
    }
  __syncthreads();
  if (tid < 128) {
    float2 p0 = red[tid][0], p1 = red[tid][1];
    float M = fmaxf(p0.x, p1.x);
    float S = p0.y * __expf(p0.x - M) + p1.y * __expf(p1.x - M);
    lsep[(size_t)(rowBase + tid) * NGRP + cb] = M + logf(S);
  }

  // pass 3: column partials -> lsep[col][rb]  (off-diagonal tiles only)
  if (rb != cb) {
    __syncthreads();
#pragma unroll
    for (int n = 0; n < 4; ++n) {
      float cm = -INFINITY;
#pragma unroll
      for (int m = 0; m < 4; ++m)
#pragma unroll
        for (int v = 0; v < 4; ++v) cm = fmaxf(cm, acc[m][n][v]);
      cm = fmaxf(cm, __shfl_xor(cm, 16));
      cm = fmaxf(cm, __shfl_xor(cm, 32));
      float cs = 0.f;
#pragma unroll
      for (int m = 0; m < 4; ++m)
#pragma unroll
        for (int v = 0; v < 4; ++v) cs += __expf(acc[m][n][v] - cm);
      cs += __shfl_xor(cs, 16);
      cs += __shfl_xor(cs, 32);
      if (lane < 16) red[wc * 64 + n * 16 + lane][wr] = make_float2(cm, cs);
    }
    __syncthreads();
    if (tid < 128) {
      float2 p0 = red[tid][0], p1 = red[tid][1];
      float M = fmaxf(p0.x, p1.x);
      float S = p0.y * __expf(p0.x - M) + p1.y * __expf(p1.x - M);
      lsep[(size_t)(colBase + tid) * NGRP + rb] = M + logf(S);
    }
  }
}

// ---------------------------------------------------------------------------
// P2+P3: 16 blocks x 256 thr, 1 row/thread; last finisher (fetch_add == 15)
// sums the 16 partials in fixed order and resets the counter (R6-proven).
// ---------------------------------------------------------------------------
__global__ __launch_bounds__(256) void reduce_final(
    const float* __restrict__ lsep, const float* __restrict__ pos,
    float* __restrict__ partial, float* __restrict__ out) {
  const int tid = threadIdx.x;
  const int row = blockIdx.x * 256 + tid;
  const float* lp = lsep + (size_t)row * NGRP;
  float M = lp[0];
#pragma unroll
  for (int k = 1; k < NGRP; ++k) M = fmaxf(M, lp[k]);
  float s = 0.f;
#pragma unroll
  for (int k = 0; k < NGRP; ++k) s += __expf(lp[k] - M);
  float contrib = (M + logf(s)) - pos[row];

  __shared__ float fr[256];
  fr[tid] = contrib;
  __syncthreads();
#pragma unroll
  for (int off = 128; off > 0; off >>= 1) {
    if (tid < off) fr[tid] += fr[tid + off];
    __syncthreads();
  }
  if (tid == 0) {
    partial[blockIdx.x] = fr[0];
    unsigned v = __hip_atomic_fetch_add(&red_done, 1u, __ATOMIC_ACQ_REL,
                                        __HIP_MEMORY_SCOPE_AGENT);
    if (v == 15u) {
      float tot = 0.f;
      for (int k = 0; k < 16; ++k) tot += partial[k];
      out[0] = tot * (1.0f / 4096.0f);
      __hip_atomic_store(&red_done, 0u, __ATOMIC_RELAXED,
                         __HIP_MEMORY_SCOPE_AGENT);
    }
  }
}

// ===========================================================================
extern "C" void kernel_launch(void* const* d_in, const int* in_sizes, int n_in,
                              void* d_out, int out_size, void* d_ws, size_t ws_size,
                              hipStream_t stream) {
  const float* mu_x    = (const float*)d_in[1];
  const float* sigma_x = (const float*)d_in[2];
  const float* mu_p    = (const float*)d_in[3];
  const float* sigma_p = (const float*)d_in[4];
  float* out = (float*)d_out;

  float to_add = (float)(-log((4095.0 - 1.0 / 5.0) / 4094.0));

  const size_t featB = (size_t)N_TOT * K_DIM * 2;   // 4 MB
  char* ws = (char*)d_ws;
  __hip_bfloat16* Gf = (__hip_bfloat16*)(ws);
  float* a       = (float*)(ws + featB);                    // 16 KB
  float* lsep    = (float*)(ws + featB + 16384);            // 512 KB
  float* pos     = (float*)(ws + featB + 16384 + 524288);   // 16 KB
  float* partial = (float*)(ws + featB + 16384 + 524288 + 16384);

  prep_feat<<<dim3(256), dim3(256), 0, stream>>>(mu_x, sigma_x, mu_p, sigma_p,
                                                 Gf, a);
  gemm_lse<<<dim3(NBLK), dim3(256), 0, stream>>>(Gf, a, lsep, pos, to_add);
  reduce_final<<<dim3(16), dim3(256), 0, stream>>>(lsep, pos, partial, out);
}